// Round 5
// baseline (354.616 us; speedup 1.0000x reference)
//
#include <hip/hip_runtime.h>

// ---- problem constants ----
#define TT 100
#define BB 1024
#define NI 256
#define NH 512
#define NO 10
#define GK 512                 // doubled K (hi/lo interleave)

// output layout (floats), return order: cur1, cur2, spk1, spk2, mem1, mem2
constexpr long long C1_OFF = 0;
constexpr long long C2_OFF = 52428800LL;
constexpr long long S1_OFF = 53452800LL;
constexpr long long S2_OFF = 105881600LL;
constexpr long long M1_OFF = 106905600LL;
constexpr long long M2_OFF = 159334400LL;

typedef short bf16x8 __attribute__((ext_vector_type(8)));
typedef float f32x4 __attribute__((ext_vector_type(4)));

__device__ __forceinline__ unsigned int rne_bf16(float f) {
    unsigned int u = __float_as_uint(f);
    return (u + 0x7fffu + ((u >> 16) & 1u)) >> 16;
}

// f32 -> packed [hi,lo] bf16 pair (Dekker split), bit-identical to prior rounds
__device__ __forceinline__ unsigned int pack_hilo(float f) {
    unsigned int hi = rne_bf16(f);
    float hif = __uint_as_float(hi << 16);
    float e = f - hif;
    unsigned int lo = rne_bf16(e);
    return (hi & 0xffffu) | (lo << 16);
}

__device__ __forceinline__ void pack4(uint4& d, const float4& a) {
    d.x = pack_hilo(a.x); d.y = pack_hilo(a.y); d.z = pack_hilo(a.z); d.w = pack_hilo(a.w);
}

// LDS-only barrier: order ds_write handoff WITHOUT draining the global store
// stream (HIP __syncthreads would emit s_waitcnt vmcnt(0) and stall the CU on
// 13 outstanding HBM writes every t-step). Stores self-pace via vmcnt backpressure.
__device__ __forceinline__ void barrier_lds() {
    asm volatile("s_waitcnt lgkmcnt(0)" ::: "memory");
    __builtin_amdgcn_s_barrier();
}

// ---- prep: W1 (f32 {0,0.5}) -> bf16 duplicated pairs, linear [h][gk] ----
__global__ void prep_w_kernel(const float* __restrict__ W1, short* __restrict__ Wp) {
    int i = blockIdx.x * blockDim.x + threadIdx.x;
    if (i >= NH * NI / 4) return;
    float4 v = ((const float4*)W1)[i];
    float f[4] = {v.x, v.y, v.z, v.w};
    uint4 o;
    unsigned int* op = &o.x;
    #pragma unroll
    for (int j = 0; j < 4; ++j) {
        unsigned int hb = __float_as_uint(f[j]) >> 16;   // exact for 0 / 0.5
        op[j] = hb | (hb << 16);
    }
    ((uint4*)Wp)[i] = o;
}

// ---- zero C2 (atomic accumulation target) ----
__global__ void zero_c2_kernel(float* __restrict__ c2) {
    int i = blockIdx.x * blockDim.x + threadIdx.x;
    if (i < TT * BB * NO / 4) ((float4*)c2)[i] = float4{0.f, 0.f, 0.f, 0.f};
}

// ---- fused GEMM1 + LIF1 + partial GEMM2 (atomic) ----
// Block owns (32 b) x (64 h) for ALL t; W1 chunk LDS-resident (swizzled);
// m1 in registers across t. Per t: stage x (dbuf, 2-deep reg prefetch),
// 16-kt MFMA chain (bit-identical order), in-register LIF1, store c1/s1/m1
// (store-only), ballot spikes, atomicAdd 0.5*popcnt partial cur2 into C2.
// One LDS-only barrier per t.
__launch_bounds__(512, 1)
__global__ void fused_kernel(const float* __restrict__ x, const short* __restrict__ Wp,
                             const float* __restrict__ W2, float* __restrict__ out) {
    __shared__ short Wl[64][512];          // 64 KB resident W chunk (16B-unit XOR swz)
    __shared__ short Al[2][32][512];       // 64 KB x-tile double buffer (same swz)
    __shared__ unsigned long long bal[2][8][4];
    __shared__ unsigned long long w2m_lds[NO];

    const int tid = threadIdx.x;
    const int bid = blockIdx.x;
    // XCD grouping: 8 h-chunk blocks of one b-group share an XCD (bid&7)
    const int xcd = bid & 7;
    const int j8  = bid >> 3;              // 0..31
    const int bgrp = xcd * 4 + (j8 >> 3);  // 0..31 (bijective)
    const int nc   = j8 & 7;               // 0..7
    const int b0 = bgrp * 32;
    const int n0 = nc * 64;

    const int wid = tid >> 6;              // 0..7 (2m x 4n waves)
    const int lane = tid & 63;
    const int mw = wid >> 2;               // 0..1
    const int nw = wid & 3;                // 0..3
    const int fr = lane & 15;
    const int g  = lane >> 4;              // 0..3
    const int mrow = mw * 16 + fr;
    const int nrow = nw * 16 + fr;

    // ---- prologue ----
    if (wid == 0) {
        #pragma unroll
        for (int o = 0; o < NO; ++o)
            w2m_lds[o] = __ballot(W2[o * NH + n0 + lane] != 0.0f);
    }
    #pragma unroll
    for (int u8 = 0; u8 < 8; ++u8) {       // W chunk: 4096 16B units, coalesced
        int e = u8 * 512 + tid;
        int r = e >> 6, u = e & 63;
        uint4 v = ((const uint4*)Wp)[(long long)n0 * 64 + e];
        *(uint4*)&Wl[r][((u ^ (r & 7)) * 8)] = v;
    }
    const int arow = tid >> 4;             // 0..31
    const int au0 = (tid & 15) * 4;
    {
        const float* xs = x + ((long long)b0 + arow) * NI;
        #pragma unroll
        for (int uu = 0; uu < 4; ++uu) {
            float4 a = *(const float4*)&xs[(au0 + uu) * 4];
            uint4 pa; pack4(pa, a);
            *(uint4*)&Al[0][arow][(((au0 + uu) ^ (arow & 7)) * 8)] = pa;
        }
    }
    float4 rawOdd[4], rawEven[4];          // x(1) / x(2)
    #pragma unroll
    for (int uu = 0; uu < 4; ++uu) {
        rawOdd[uu]  = *(const float4*)&x[((long long)1 * BB + b0 + arow) * NI + (au0 + uu) * 4];
        rawEven[uu] = *(const float4*)&x[((long long)2 * BB + b0 + arow) * NI + (au0 + uu) * 4];
    }
    __syncthreads();
    unsigned long long w2m_reg = (tid < 32 * NO) ? w2m_lds[tid >> 5] : 0ULL;

    float m1v[4] = {0.f, 0.f, 0.f, 0.f};

    auto step = [&](int T, float4 (&RAW)[4]) {
        f32x4 a = {0.f, 0.f, 0.f, 0.f};
        #pragma unroll
        for (int kt = 0; kt < 16; ++kt) {
            bf16x8 af = *(const bf16x8*)&Al[T & 1][mrow][(((kt * 4 + g) ^ (fr & 7)) * 8)];
            bf16x8 wf = *(const bf16x8*)&Wl[nrow][(((kt * 4 + g) ^ (fr & 7)) * 8)];
            a = __builtin_amdgcn_mfma_f32_16x16x32_bf16(af, wf, a, 0, 0, 0);
        }
        float s1v[4];
        #pragma unroll
        for (int r = 0; r < 4; ++r) {
            float c1 = a[r];
            float rst = (m1v[r] > 1.0f) ? 1.0f : 0.0f;
            m1v[r] = 0.9f * m1v[r] + c1 - rst;
            s1v[r] = (m1v[r] > 1.0f) ? 1.0f : 0.0f;
            long long ob = ((long long)T * BB + b0 + mw * 16 + g * 4 + r) * NH + n0 + nw * 16 + fr;
            out[C1_OFF + ob] = c1;
            out[S1_OFF + ob] = s1v[r];
            out[M1_OFF + ob] = m1v[r];
        }
        #pragma unroll
        for (int r = 0; r < 4; ++r) {
            unsigned long long bm = __ballot(s1v[r] != 0.0f);
            if (lane == 0) bal[T & 1][wid][r] = bm;
        }
        if (T + 1 < TT) {
            #pragma unroll
            for (int uu = 0; uu < 4; ++uu) {
                uint4 pa; pack4(pa, RAW[uu]);
                *(uint4*)&Al[(T + 1) & 1][arow][(((au0 + uu) ^ (arow & 7)) * 8)] = pa;
            }
            int tl = (T + 3 < TT) ? T + 3 : TT - 1;
            #pragma unroll
            for (int uu = 0; uu < 4; ++uu)
                RAW[uu] = *(const float4*)&x[((long long)tl * BB + b0 + arow) * NI + (au0 + uu) * 4];
        }
        barrier_lds();   // LDS handoff only; global stores stay in flight
        if (tid < 32 * NO) {
            int r = tid & 31, o = tid >> 5;
            int mwr = r >> 4, l15 = r & 15;
            unsigned long long row64 = 0;
            #pragma unroll
            for (int nwx = 0; nwx < 4; ++nwx)
                row64 |= ((bal[T & 1][mwr * 4 + nwx][l15 & 3] >> ((l15 >> 2) * 16)) & 0xFFFFULL)
                         << (16 * nwx);
            int cnt = __popcll(row64 & w2m_reg);
            atomicAdd(out + C2_OFF + ((long long)T * BB + b0 + r) * NO + o, 0.5f * (float)cnt);
        }
    };

    for (int tp = 0; tp < TT; tp += 2) {
        step(tp,     rawOdd);
        step(tp + 1, rawEven);
    }
}

// ---- LIF2: m2 recurrence over completed C2 (4 MB, L3-hot) ----
__launch_bounds__(512)
__global__ void lif2_kernel(float* __restrict__ out) {
    int j = blockIdx.x * 512 + threadIdx.x;
    if (j >= BB * NO) return;
    const float* c2p = out + C2_OFF + j;
    float* s2p = out + S2_OFF + j;
    float* m2p = out + M2_OFF + j;
    const int st = BB * NO;
    float m2 = 0.f;
    float v[4];
    #pragma unroll
    for (int k = 0; k < 4; ++k) v[k] = c2p[(long long)k * st];
    for (int t = 0; t < TT; t += 4) {
        #pragma unroll
        for (int k = 0; k < 4; ++k) {
            float c2 = v[k];
            if (t + 4 + k < TT) v[k] = c2p[(long long)(t + 4 + k) * st];
            float rst = (m2 > 1.0f) ? 1.0f : 0.0f;
            m2 = 0.8f * m2 + c2 - rst;
            float s2 = (m2 > 1.0f) ? 1.0f : 0.0f;
            s2p[(long long)(t + k) * st] = s2;
            m2p[(long long)(t + k) * st] = m2;
        }
    }
}

extern "C" void kernel_launch(void* const* d_in, const int* in_sizes, int n_in,
                              void* d_out, int out_size, void* d_ws, size_t ws_size,
                              hipStream_t stream) {
    const float* x  = (const float*)d_in[0];
    const float* W1 = (const float*)d_in[1];
    const float* W2 = (const float*)d_in[2];
    float* out = (float*)d_out;

    // Wp scratch (512 KB) in the S2 region: read only by fused_kernel's prologue,
    // overwritten only by lif2_kernel (strictly after). Stream-ordered safe.
    short* Wp = (short*)(out + S2_OFF);

    prep_w_kernel<<<(NH * NI / 4 + 255) / 256, 256, 0, stream>>>(W1, Wp);
    zero_c2_kernel<<<(TT * BB * NO / 4 + 255) / 256, 256, 0, stream>>>(out + C2_OFF);
    fused_kernel<<<256, 512, 0, stream>>>(x, Wp, W2, out);
    lif2_kernel<<<(BB * NO + 511) / 512, 512, 0, stream>>>(out);
}